// Round 1
// baseline (181.974 us; speedup 1.0000x reference)
//
#include <hip/hip_runtime.h>

typedef unsigned short ushort_t;
typedef __attribute__((ext_vector_type(8))) short short8;
typedef __attribute__((ext_vector_type(8))) unsigned short ushort8;
typedef __attribute__((ext_vector_type(4))) float f32x4;

__device__ __forceinline__ ushort_t f2bf(float f) {
  union { float f; unsigned int u; } x; x.f = f;
  unsigned int r = x.u + 0x7fffu + ((x.u >> 16) & 1u);
  return (ushort_t)(r >> 16);
}

// async global->LDS, 16B per lane. LDS base must be wave-uniform; HW adds lane*16.
__device__ __forceinline__ void async16(const void* g, void* lds_uniform) {
  __builtin_amdgcn_global_load_lds(
      (const __attribute__((address_space(1))) void*)g,
      (__attribute__((address_space(3))) void*)lds_uniform, 16, 0, 0);
}

// ---------------- converts ----------------
__global__ void conv_x(const float* __restrict__ in, ushort_t* __restrict__ o, int n4) {
  int i = blockIdx.x * blockDim.x + threadIdx.x;
  if (i < n4) {
    float4 f = ((const float4*)in)[i];
    typedef __attribute__((ext_vector_type(4))) unsigned short us4;
    us4 u;
    u[0] = f2bf(f.x); u[1] = f2bf(f.y); u[2] = f2bf(f.z); u[3] = f2bf(f.w);
    ((us4*)o)[i] = u;
  }
}

// in: fp32 [R][Cc] -> out: bf16 [Cc][R]
__global__ void transpose_conv(const float* __restrict__ in, ushort_t* __restrict__ out,
                               int R, int Cc) {
  __shared__ float tile[32][33];
  const int bx = blockIdx.x * 32;
  const int by = blockIdx.y * 32;
  const int tx = threadIdx.x, ty = threadIdx.y;
  #pragma unroll
  for (int i = ty; i < 32; i += 8)
    tile[i][tx] = in[(size_t)(by + i) * Cc + bx + tx];
  __syncthreads();
  #pragma unroll
  for (int i = ty; i < 32; i += 8)
    out[(size_t)(bx + i) * R + by + tx] = f2bf(tile[tx][i]);
}

// ---------------- GEMM: C[M,N] = A[M,K] * Bt[N,K]^T, K=1024, 128x128 tile ----------------
// MODE 0: qkv scatter epilogue -> q/k/v [B*H][N][D] bf16
// MODE 1: +bias, fp32 output
template<int MODE>
__global__ __launch_bounds__(256) void gemm128(
    const ushort_t* __restrict__ A, const ushort_t* __restrict__ Bt,
    ushort_t* __restrict__ o0, ushort_t* __restrict__ o1, ushort_t* __restrict__ o2,
    const float* __restrict__ bias, float* __restrict__ fout)
{
  constexpr int K = 1024;
  __shared__ __align__(16) ushort_t As[128 * 64];
  __shared__ __align__(16) ushort_t Bs[128 * 64];
  const int tm = blockIdx.y * 128;
  const int tn = blockIdx.x * 128;
  const int tid = threadIdx.x;
  const int w = tid >> 6, lane = tid & 63;
  const int wr = (w >> 1) * 64, wc = (w & 1) * 64;
  const int l15 = lane & 15, lk = (lane >> 4) * 8;
  f32x4 acc[4][4] = {};

  for (int k0 = 0; k0 < K; k0 += 64) {
    #pragma unroll
    for (int j = 0; j < 4; ++j) {
      const int c = w * 4 + j;
      const int boff = c * 1024 + lane * 16;   // byte offset in 16KB tile
      const int row = boff >> 7;               // row stride 128B (64 bf16)
      const int ke = (boff & 127) >> 1;
      async16(A + (size_t)(tm + row) * K + k0 + ke, (char*)As + c * 1024);
      async16(Bt + (size_t)(tn + row) * K + k0 + ke, (char*)Bs + c * 1024);
    }
    __syncthreads();
    #pragma unroll
    for (int kk = 0; kk < 2; ++kk) {
      short8 af[4], bfr[4];
      #pragma unroll
      for (int i = 0; i < 4; ++i) {
        af[i]  = *(const short8*)&As[(wr + i * 16 + l15) * 64 + kk * 32 + lk];
        bfr[i] = *(const short8*)&Bs[(wc + i * 16 + l15) * 64 + kk * 32 + lk];
      }
      #pragma unroll
      for (int i = 0; i < 4; ++i)
        #pragma unroll
        for (int j = 0; j < 4; ++j)
          acc[i][j] = __builtin_amdgcn_mfma_f32_16x16x32_bf16(af[i], bfr[j], acc[i][j], 0, 0, 0);
    }
    __syncthreads();
  }

  if (MODE == 0) {
    #pragma unroll
    for (int j = 0; j < 4; ++j) {
      const int col = tn + wc + j * 16 + l15;      // 0..3071
      const int which = col >> 10;
      const int h = (col >> 6) & 15, d = col & 63;
      ushort_t* dst = (which == 0) ? o0 : ((which == 1) ? o1 : o2);
      #pragma unroll
      for (int i = 0; i < 4; ++i)
        #pragma unroll
        for (int r = 0; r < 4; ++r) {
          const int m = tm + wr + i * 16 + (lane >> 4) * 4 + r;  // 0..8191
          const int b = m >> 12, n = m & 4095;
          dst[(size_t)((b * 16 + h) * 4096 + n) * 64 + d] = f2bf(acc[i][j][r]);
        }
    }
  } else {
    #pragma unroll
    for (int j = 0; j < 4; ++j) {
      const int col = tn + wc + j * 16 + l15;      // 0..1023
      const float bv = bias[col];
      #pragma unroll
      for (int i = 0; i < 4; ++i)
        #pragma unroll
        for (int r = 0; r < 4; ++r) {
          const int m = tm + wr + i * 16 + (lane >> 4) * 4 + r;
          fout[(size_t)m * 1024 + col] = acc[i][j][r] + bv;
        }
    }
  }
}

// ---------------- sliding-window attention ----------------
// grid (32 qblk, 32 bh); 256 threads = 4 waves; wave w owns 32 query rows.
__global__ __launch_bounds__(256) void swin_attn(
    const ushort_t* __restrict__ qb, const ushort_t* __restrict__ kb,
    const ushort_t* __restrict__ vb, ushort_t* __restrict__ attn_out)
{
  constexpr int N = 4096;
  __shared__ __align__(16) ushort_t Ks[64 * 64];    // [key][d]
  __shared__ __align__(16) ushort_t VT[64 * 64];    // [d][key]
  __shared__ __align__(16) ushort_t Pw[4][32 * 64]; // per-wave [q][key]
  const int qblk = blockIdx.x;
  const int bh = blockIdx.y;
  const int tid = threadIdx.x;
  const int w = tid >> 6, lane = tid & 63;
  const int l15 = lane & 15, lq = lane >> 4;
  const size_t base = (size_t)bh * N * 64;
  const int q0 = qblk * 128 + w * 32;

  // Q fragments in registers (reused across all key tiles)
  short8 qf[2][2];
  #pragma unroll
  for (int fm = 0; fm < 2; ++fm)
    #pragma unroll
    for (int kk = 0; kk < 2; ++kk)
      qf[fm][kk] = *(const short8*)&qb[base + (size_t)(q0 + fm * 16 + l15) * 64 + kk * 32 + lq * 8];

  f32x4 oacc[2][4] = {};
  float mrun[2][4], lrun[2][4];
  #pragma unroll
  for (int fm = 0; fm < 2; ++fm)
    #pragma unroll
    for (int r = 0; r < 4; ++r) { mrun[fm][r] = 0.f; lrun[fm][r] = 0.f; }

  for (int t = 0; t < 6; ++t) {
    const int kpos0 = qblk * 128 - 128 + t * 64;
    if (kpos0 + 63 < 0 || kpos0 >= N) continue;   // uniform skip
    __syncthreads();                               // prev-tile LDS reads done
    // stage K [64][64] via async copy (clamped rows are masked later)
    #pragma unroll
    for (int j = 0; j < 2; ++j) {
      const int c = w * 2 + j;
      const int boff = c * 1024 + lane * 16;
      const int row = boff >> 7;
      const int de = (boff & 127) >> 1;
      int kp = kpos0 + row; kp = kp < 0 ? 0 : (kp > N - 1 ? N - 1 : kp);
      async16(kb + base + (size_t)kp * 64 + de, (char*)Ks + c * 1024);
    }
    // stage V transposed: thread t -> key=t/4, 16 d's
    {
      const int key = tid >> 2;
      const int dbase = (tid & 3) * 16;
      int kp = kpos0 + key; kp = kp < 0 ? 0 : (kp > N - 1 ? N - 1 : kp);
      const ushort_t* src = vb + base + (size_t)kp * 64 + dbase;
      ushort8 v0 = *(const ushort8*)src;
      ushort8 v1 = *(const ushort8*)(src + 8);
      #pragma unroll
      for (int i = 0; i < 8; ++i) VT[(dbase + i) * 64 + key] = v0[i];
      #pragma unroll
      for (int i = 0; i < 8; ++i) VT[(dbase + 8 + i) * 64 + key] = v1[i];
    }
    __syncthreads();

    // S = Q K^T  (per wave: 32 q x 64 keys)
    f32x4 sacc[2][4] = {};
    #pragma unroll
    for (int kk = 0; kk < 2; ++kk) {
      short8 kf[4];
      #pragma unroll
      for (int fn = 0; fn < 4; ++fn)
        kf[fn] = *(const short8*)&Ks[(fn * 16 + l15) * 64 + kk * 32 + lq * 8];
      #pragma unroll
      for (int fm = 0; fm < 2; ++fm)
        #pragma unroll
        for (int fn = 0; fn < 4; ++fn)
          sacc[fm][fn] = __builtin_amdgcn_mfma_f32_16x16x32_bf16(qf[fm][kk], kf[fn], sacc[fm][fn], 0, 0, 0);
    }

    // mask + online softmax (row = fm*16 + lq*4 + r; 16 cols live in the 16 lanes of a quarter)
    #pragma unroll
    for (int fm = 0; fm < 2; ++fm) {
      #pragma unroll
      for (int r = 0; r < 4; ++r) {
        const int qpos = qblk * 128 + w * 32 + fm * 16 + lq * 4 + r;
        float s[4]; float mx = -1e30f;
        #pragma unroll
        for (int fn = 0; fn < 4; ++fn) {
          const int kpos = kpos0 + fn * 16 + l15;
          const int dd = kpos - qpos;
          const bool valid = (kpos >= 0) && (kpos < N) && (dd <= 128) && (dd >= -128);
          s[fn] = valid ? sacc[fm][fn][r] * 0.125f : -1e30f;
          mx = fmaxf(mx, s[fn]);
        }
        mx = fmaxf(mx, __shfl_xor(mx, 1));
        mx = fmaxf(mx, __shfl_xor(mx, 2));
        mx = fmaxf(mx, __shfl_xor(mx, 4));
        mx = fmaxf(mx, __shfl_xor(mx, 8));
        const float mnew = fmaxf(mrun[fm][r], mx);
        const float fac = __expf(mrun[fm][r] - mnew);
        float rs = 0.f;
        #pragma unroll
        for (int fn = 0; fn < 4; ++fn) {
          const float p = __expf(s[fn] - mnew);
          rs += p;
          Pw[w][(fm * 16 + lq * 4 + r) * 64 + fn * 16 + l15] = f2bf(p);
        }
        rs += __shfl_xor(rs, 1); rs += __shfl_xor(rs, 2);
        rs += __shfl_xor(rs, 4); rs += __shfl_xor(rs, 8);
        lrun[fm][r] = lrun[fm][r] * fac + rs;
        mrun[fm][r] = mnew;
        #pragma unroll
        for (int fn = 0; fn < 4; ++fn)
          oacc[fm][fn][r] *= fac;
      }
    }

    // O += P V   (P from wave-private LDS, V^T from LDS)
    #pragma unroll
    for (int kk = 0; kk < 2; ++kk) {
      short8 pf[2], vf[4];
      #pragma unroll
      for (int fm = 0; fm < 2; ++fm)
        pf[fm] = *(const short8*)&Pw[w][(fm * 16 + l15) * 64 + kk * 32 + lq * 8];
      #pragma unroll
      for (int fn = 0; fn < 4; ++fn)
        vf[fn] = *(const short8*)&VT[(fn * 16 + l15) * 64 + kk * 32 + lq * 8];
      #pragma unroll
      for (int fm = 0; fm < 2; ++fm)
        #pragma unroll
        for (int fn = 0; fn < 4; ++fn)
          oacc[fm][fn] = __builtin_amdgcn_mfma_f32_16x16x32_bf16(pf[fm], vf[fn], oacc[fm][fn], 0, 0, 0);
    }
  }

  // normalize + write [B*N][C] bf16, col = h*64+d
  const int b = bh >> 4, h = bh & 15;
  #pragma unroll
  for (int fm = 0; fm < 2; ++fm)
    #pragma unroll
    for (int fn = 0; fn < 4; ++fn)
      #pragma unroll
      for (int r = 0; r < 4; ++r) {
        const int qpos = qblk * 128 + w * 32 + fm * 16 + lq * 4 + r;
        const int d = fn * 16 + l15;
        const float o = oacc[fm][fn][r] / lrun[fm][r];
        attn_out[(size_t)(b * 4096 + qpos) * 1024 + h * 64 + d] = f2bf(o);
      }
}

// ---------------- launch ----------------
extern "C" void kernel_launch(void* const* d_in, const int* in_sizes, int n_in,
                              void* d_out, int out_size, void* d_ws, size_t ws_size,
                              hipStream_t stream) {
  const float* x      = (const float*)d_in[0];
  const float* w_qkv  = (const float*)d_in[1];
  const float* w_proj = (const float*)d_in[2];
  const float* b_proj = (const float*)d_in[3];
  float* out = (float*)d_out;
  char* ws = (char*)d_ws;

  // workspace layout (bytes); attn16 aliases x16 (dead after qkv GEMM)
  ushort_t* x16    = (ushort_t*)(ws);                 // 16,777,216  (also attn_out bf16)
  ushort_t* wqkvT  = (ushort_t*)(ws + 16777216);      //  6,291,456
  ushort_t* wprojT = (ushort_t*)(ws + 23068672);      //  2,097,152
  ushort_t* qbuf   = (ushort_t*)(ws + 25165824);      // 16,777,216
  ushort_t* kbuf   = (ushort_t*)(ws + 41943040);      // 16,777,216
  ushort_t* vbuf   = (ushort_t*)(ws + 58720256);      // 16,777,216 -> total 75,497,472
  ushort_t* attn16 = x16;

  conv_x<<<dim3(8192), dim3(256), 0, stream>>>(x, x16, 2097152);
  transpose_conv<<<dim3(96, 32), dim3(32, 8), 0, stream>>>(w_qkv, wqkvT, 1024, 3072);
  transpose_conv<<<dim3(32, 32), dim3(32, 8), 0, stream>>>(w_proj, wprojT, 1024, 1024);
  gemm128<0><<<dim3(24, 64), dim3(256), 0, stream>>>(x16, wqkvT, qbuf, kbuf, vbuf, nullptr, nullptr);
  swin_attn<<<dim3(32, 32), dim3(256), 0, stream>>>(qbuf, kbuf, vbuf, attn16);
  gemm128<1><<<dim3(8, 64), dim3(256), 0, stream>>>(attn16, wprojT, nullptr, nullptr, nullptr, b_proj, out);
}

// Round 3
// 171.775 us; speedup vs baseline: 1.0594x; 1.0594x over previous
//
#include <hip/hip_runtime.h>

typedef unsigned short ushort_t;
typedef __attribute__((ext_vector_type(8))) short short8;
typedef __attribute__((ext_vector_type(8))) unsigned short ushort8;
typedef __attribute__((ext_vector_type(4))) float f32x4;

__device__ __forceinline__ ushort_t f2bf(float f) {
  union { float f; unsigned int u; } x; x.f = f;
  unsigned int r = x.u + 0x7fffu + ((x.u >> 16) & 1u);
  return (ushort_t)(r >> 16);
}

// async global->LDS, 16B per lane. LDS base must be wave-uniform; HW adds lane*16.
__device__ __forceinline__ void async16(const void* g, void* lds_uniform) {
  __builtin_amdgcn_global_load_lds(
      (const __attribute__((address_space(1))) void*)g,
      (__attribute__((address_space(3))) void*)lds_uniform, 16, 0, 0);
}

// ---------------- converts ----------------
__global__ void conv_x(const float* __restrict__ in, ushort_t* __restrict__ o, int n4) {
  int i = blockIdx.x * blockDim.x + threadIdx.x;
  if (i < n4) {
    float4 f = ((const float4*)in)[i];
    typedef __attribute__((ext_vector_type(4))) unsigned short us4;
    us4 u;
    u[0] = f2bf(f.x); u[1] = f2bf(f.y); u[2] = f2bf(f.z); u[3] = f2bf(f.w);
    ((us4*)o)[i] = u;
  }
}

// in: fp32 [R][Cc] -> out: bf16 [Cc][R]
__global__ void transpose_conv(const float* __restrict__ in, ushort_t* __restrict__ out,
                               int R, int Cc) {
  __shared__ float tile[32][33];
  const int bx = blockIdx.x * 32;
  const int by = blockIdx.y * 32;
  const int tx = threadIdx.x, ty = threadIdx.y;
  #pragma unroll
  for (int i = ty; i < 32; i += 8)
    tile[i][tx] = in[(size_t)(by + i) * Cc + bx + tx];
  __syncthreads();
  #pragma unroll
  for (int i = ty; i < 32; i += 8)
    out[(size_t)(bx + i) * R + by + tx] = f2bf(tile[tx][i]);
}

// ---------------- 256x256 8-phase GEMM: C[M,N] = A[M,K] * Bt[N,K]^T, K=1024 ----------------
// 512 threads = 8 waves (2M x 4N). LDS 128KB = 2 dbuf x {A,B} x 4 groups x 8KB.
// Staged-unit grouping matches phase readers ACROSS waves:
//   A group g (64 rows) = global rows (g&1)*128 + (g>>1)*64 + 0..63   (g = IH*2 + wm)
//   B group g = two 32-row slices: n = (g&1)*128 + slice*64 + (g>>1)*32 + 0..31 (g = FH*2 + (wn>>1))
// Col swizzle: 16B-unit q of group-row r holds k-elems ((q ^ (r&7))*8); inverse applied on
// the per-lane GLOBAL source (LDS dest stays linear), same XOR on ds_read addr.
// MODE 0: qkv scatter epilogue -> q/k/v [B*H][N][D] bf16.  MODE 1: +bias, fp32 out.
template<int MODE, int NTX>
__global__ __launch_bounds__(512, 2) void gemm256(
    const ushort_t* __restrict__ A, const ushort_t* __restrict__ Bt,
    ushort_t* __restrict__ o0, ushort_t* __restrict__ o1, ushort_t* __restrict__ o2,
    const float* __restrict__ bias, float* __restrict__ fout, int nwg)
{
  constexpr int K = 1024;
  constexpr int KT = K / 64;       // 16 K-tiles
  __shared__ __align__(16) char Lds[131072];

  // XCD-bijective block swizzle (nwg % 8 == 0)
  const int bid = blockIdx.x;
  const int cpx = nwg >> 3;
  const int wg = (bid & 7) * cpx + (bid >> 3);
  const int bx = wg % NTX, by = wg / NTX;
  const int tm = by * 256, tn = bx * 256;

  const int tid = threadIdx.x;
  const int w = tid >> 6, lane = tid & 63;
  const int wm = w >> 2, wn = w & 3;
  const int l15 = lane & 15, lq = lane >> 4;

  // ---- staging geometry ----
  const int sr = (w << 3) + (lane >> 3);              // 0..63 row within a unit
  const int scol = ((lane & 7) ^ (lane >> 3)) << 3;   // inverse-swizzled k-offset (elems)
  const ushort_t* agA = A  + (size_t)(tm + sr) * K + scol;
  const ushort_t* bgB = Bt + (size_t)(tn + ((sr >> 5) << 6) + (sr & 31)) * K + scol;

  // ---- ds_read geometry ----
  const int offk0 = ((lq ^ (l15 & 7)) << 4);          // kk=0 swizzled byte off
  const int offk1 = (((4 + lq) ^ (l15 & 7)) << 4);    // kk=1
  char* aRead = Lds + (wm << 13) + (l15 << 7);                              // + IH*16384 + i*2048
  char* bRead = Lds + 32768 + ((wn >> 1) << 13) + ((((wn & 1) << 5) + l15) << 7); // + FH*16384 + f*2048

  short8 af[4][2];
  short8 bf[2][2];
  f32x4 acc[8][4] = {};

#define LDA(BUF, IH) \
  _Pragma("unroll") for (int i_ = 0; i_ < 4; ++i_) { \
    af[i_][0] = *(const short8*)(aRead + (BUF)*65536 + (IH)*16384 + i_*2048 + offk0); \
    af[i_][1] = *(const short8*)(aRead + (BUF)*65536 + (IH)*16384 + i_*2048 + offk1); }

#define LDB(BUF, FH) \
  _Pragma("unroll") for (int f_ = 0; f_ < 2; ++f_) { \
    bf[f_][0] = *(const short8*)(bRead + (BUF)*65536 + (FH)*16384 + f_*2048 + offk0); \
    bf[f_][1] = *(const short8*)(bRead + (BUF)*65536 + (FH)*16384 + f_*2048 + offk1); }

#define MMA(IH, FH) \
  _Pragma("unroll") for (int i_ = 0; i_ < 4; ++i_) \
    _Pragma("unroll") for (int f_ = 0; f_ < 2; ++f_) { \
      acc[(IH)*4+i_][(FH)*2+f_] = __builtin_amdgcn_mfma_f32_16x16x32_bf16(af[i_][0], bf[f_][0], acc[(IH)*4+i_][(FH)*2+f_], 0,0,0); \
      acc[(IH)*4+i_][(FH)*2+f_] = __builtin_amdgcn_mfma_f32_16x16x32_bf16(af[i_][1], bf[f_][1], acc[(IH)*4+i_][(FH)*2+f_], 0,0,0); }

  // stage A groups {PAIR*2, PAIR*2+1} of tile KT_ into buffer BUF (2 async16)
#define SA(BUF, PAIR, KT_) { \
    const ushort_t* g_ = agA + (size_t)(KT_)*64; \
    async16(g_ + (size_t)((PAIR)*64      ) * K, Lds + (BUF)*65536 + ((PAIR)*2  )*8192 + (w << 10)); \
    async16(g_ + (size_t)((PAIR)*64 + 128) * K, Lds + (BUF)*65536 + ((PAIR)*2+1)*8192 + (w << 10)); }

  // stage B groups {PAIR*2, PAIR*2+1} of tile KT_ into buffer BUF (2 async16)
#define SB(BUF, PAIR, KT_) { \
    const ushort_t* g_ = bgB + (size_t)(KT_)*64; \
    async16(g_ + (size_t)((PAIR)*32      ) * K, Lds + (BUF)*65536 + 32768 + ((PAIR)*2  )*8192 + (w << 10)); \
    async16(g_ + (size_t)((PAIR)*32 + 128) * K, Lds + (BUF)*65536 + 32768 + ((PAIR)*2+1)*8192 + (w << 10)); }

#define PHASE(DS_OPS, STG_OPS, IH, FH) \
  DS_OPS; \
  STG_OPS; \
  __builtin_amdgcn_s_barrier(); \
  asm volatile("s_waitcnt lgkmcnt(0)" ::: "memory"); \
  __builtin_amdgcn_sched_barrier(0); \
  __builtin_amdgcn_s_setprio(1); \
  MMA(IH, FH); \
  __builtin_amdgcn_s_setprio(0); \
  asm volatile("s_waitcnt vmcnt(4)" ::: "memory"); \
  __builtin_amdgcn_sched_barrier(0); \
  __builtin_amdgcn_s_barrier();

  // prologue: stage tile 0 -> buf0 in order Ag01, Bg01, Bg23, Ag23; drain first 4
  SA(0, 0, 0); SB(0, 0, 0); SB(0, 1, 0); SA(0, 1, 0);
  asm volatile("s_waitcnt vmcnt(4)" ::: "memory");
  __builtin_amdgcn_s_barrier();

  #pragma unroll 1
  for (int it = 0; it < KT / 2; ++it) {
    const int k1 = 2 * it + 1;
    const int k2 = (2 * it + 2 < KT) ? (2 * it + 2) : (KT - 1);  // clamp keeps vmcnt uniform
    // ph1-4: compute tile 2it from buf0; stage tile k1 -> buf1 (Ag01,Bg01,Bg23,Ag23)
    PHASE( LDA(0,0); LDB(0,0), SA(1,0,k1), 0, 0 );
    PHASE( LDB(0,1),           SB(1,0,k1), 0, 1 );
    PHASE( LDA(0,1),           SB(1,1,k1), 1, 1 );
    PHASE( LDB(0,0),           SA(1,1,k1), 1, 0 );
    // ph5-8: compute tile k1 from buf1; stage tile k2 -> buf0
    PHASE( LDA(1,0); LDB(1,0), SA(0,0,k2), 0, 0 );
    PHASE( LDB(1,1),           SB(0,0,k2), 0, 1 );
    PHASE( LDA(1,1),           SB(0,1,k2), 1, 1 );
    PHASE( LDB(1,0),           SA(0,1,k2), 1, 0 );
  }
  // don't exit with pending LDS writes
  asm volatile("s_waitcnt vmcnt(0)" ::: "memory");

#undef PHASE
#undef SB
#undef SA
#undef MMA
#undef LDB
#undef LDA

  if (MODE == 0) {
    #pragma unroll
    for (int f = 0; f < 4; ++f) {
      const int col = tn + wn * 64 + f * 16 + l15;       // 0..3071
      const int which = col >> 10;
      const int h = (col >> 6) & 15, d = col & 63;
      ushort_t* dst = (which == 0) ? o0 : ((which == 1) ? o1 : o2);
      #pragma unroll
      for (int i = 0; i < 8; ++i)
        #pragma unroll
        for (int r = 0; r < 4; ++r) {
          const int m = tm + wm * 128 + i * 16 + lq * 4 + r;   // 0..8191
          const int b = m >> 12, n = m & 4095;
          dst[(size_t)((b * 16 + h) * 4096 + n) * 64 + d] = f2bf(acc[i][f][r]);
        }
    }
  } else {
    #pragma unroll
    for (int f = 0; f < 4; ++f) {
      const int col = tn + wn * 64 + f * 16 + l15;       // 0..1023
      const float bv = bias[col];
      #pragma unroll
      for (int i = 0; i < 8; ++i)
        #pragma unroll
        for (int r = 0; r < 4; ++r) {
          const int m = tm + wm * 128 + i * 16 + lq * 4 + r;
          fout[(size_t)m * 1024 + col] = acc[i][f][r] + bv;
        }
    }
  }
}

// ---------------- sliding-window attention ----------------
// grid (32 qblk, 32 bh); 256 threads = 4 waves; wave w owns 32 query rows.
__global__ __launch_bounds__(256) void swin_attn(
    const ushort_t* __restrict__ qb, const ushort_t* __restrict__ kb,
    const ushort_t* __restrict__ vb, ushort_t* __restrict__ attn_out)
{
  constexpr int N = 4096;
  __shared__ __align__(16) ushort_t Ks[64 * 64];    // [key][d]
  __shared__ __align__(16) ushort_t VT[64 * 64];    // [d][key]
  __shared__ __align__(16) ushort_t Pw[4][32 * 64]; // per-wave [q][key]
  const int qblk = blockIdx.x;
  const int bh = blockIdx.y;
  const int tid = threadIdx.x;
  const int w = tid >> 6, lane = tid & 63;
  const int l15 = lane & 15, lq = lane >> 4;
  const size_t base = (size_t)bh * N * 64;
  const int q0 = qblk * 128 + w * 32;

  short8 qf[2][2];
  #pragma unroll
  for (int fm = 0; fm < 2; ++fm)
    #pragma unroll
    for (int kk = 0; kk < 2; ++kk)
      qf[fm][kk] = *(const short8*)&qb[base + (size_t)(q0 + fm * 16 + l15) * 64 + kk * 32 + lq * 8];

  f32x4 oacc[2][4] = {};
  float mrun[2][4], lrun[2][4];
  #pragma unroll
  for (int fm = 0; fm < 2; ++fm)
    #pragma unroll
    for (int r = 0; r < 4; ++r) { mrun[fm][r] = 0.f; lrun[fm][r] = 0.f; }

  for (int t = 0; t < 6; ++t) {
    const int kpos0 = qblk * 128 - 128 + t * 64;
    if (kpos0 + 63 < 0 || kpos0 >= N) continue;   // uniform skip
    __syncthreads();
    #pragma unroll
    for (int j = 0; j < 2; ++j) {
      const int c = w * 2 + j;
      const int boff = c * 1024 + lane * 16;
      const int row = boff >> 7;
      const int de = (boff & 127) >> 1;
      int kp = kpos0 + row; kp = kp < 0 ? 0 : (kp > N - 1 ? N - 1 : kp);
      async16(kb + base + (size_t)kp * 64 + de, (char*)Ks + c * 1024);
    }
    {
      const int key = tid >> 2;
      const int dbase = (tid & 3) * 16;
      int kp = kpos0 + key; kp = kp < 0 ? 0 : (kp > N - 1 ? N - 1 : kp);
      const ushort_t* src = vb + base + (size_t)kp * 64 + dbase;
      ushort8 v0 = *(const ushort8*)src;
      ushort8 v1 = *(const ushort8*)(src + 8);
      #pragma unroll
      for (int i = 0; i < 8; ++i) VT[(dbase + i) * 64 + key] = v0[i];
      #pragma unroll
      for (int i = 0; i < 8; ++i) VT[(dbase + 8 + i) * 64 + key] = v1[i];
    }
    __syncthreads();

    f32x4 sacc[2][4] = {};
    #pragma unroll
    for (int kk = 0; kk < 2; ++kk) {
      short8 kf[4];
      #pragma unroll
      for (int fn = 0; fn < 4; ++fn)
        kf[fn] = *(const short8*)&Ks[(fn * 16 + l15) * 64 + kk * 32 + lq * 8];
      #pragma unroll
      for (int fm = 0; fm < 2; ++fm)
        #pragma unroll
        for (int fn = 0; fn < 4; ++fn)
          sacc[fm][fn] = __builtin_amdgcn_mfma_f32_16x16x32_bf16(qf[fm][kk], kf[fn], sacc[fm][fn], 0, 0, 0);
    }

    #pragma unroll
    for (int fm = 0; fm < 2; ++fm) {
      #pragma unroll
      for (int r = 0; r < 4; ++r) {
        const int qpos = qblk * 128 + w * 32 + fm * 16 + lq * 4 + r;
        float s[4]; float mx = -1e30f;
        #pragma unroll
        for (int fn = 0; fn < 4; ++fn) {
          const int kpos = kpos0 + fn * 16 + l15;
          const int dd = kpos - qpos;
          const bool valid = (kpos >= 0) && (kpos < N) && (dd <= 128) && (dd >= -128);
          s[fn] = valid ? sacc[fm][fn][r] * 0.125f : -1e30f;
          mx = fmaxf(mx, s[fn]);
        }
        mx = fmaxf(mx, __shfl_xor(mx, 1));
        mx = fmaxf(mx, __shfl_xor(mx, 2));
        mx = fmaxf(mx, __shfl_xor(mx, 4));
        mx = fmaxf(mx, __shfl_xor(mx, 8));
        const float mnew = fmaxf(mrun[fm][r], mx);
        const float fac = __expf(mrun[fm][r] - mnew);
        float rs = 0.f;
        #pragma unroll
        for (int fn = 0; fn < 4; ++fn) {
          const float p = __expf(s[fn] - mnew);
          rs += p;
          Pw[w][(fm * 16 + lq * 4 + r) * 64 + fn * 16 + l15] = f2bf(p);
        }
        rs += __shfl_xor(rs, 1); rs += __shfl_xor(rs, 2);
        rs += __shfl_xor(rs, 4); rs += __shfl_xor(rs, 8);
        lrun[fm][r] = lrun[fm][r] * fac + rs;
        mrun[fm][r] = mnew;
        #pragma unroll
        for (int fn = 0; fn < 4; ++fn)
          oacc[fm][fn][r] *= fac;
      }
    }

    #pragma unroll
    for (int kk = 0; kk < 2; ++kk) {
      short8 pf[2], vf[4];
      #pragma unroll
      for (int fm = 0; fm < 2; ++fm)
        pf[fm] = *(const short8*)&Pw[w][(fm * 16 + l15) * 64 + kk * 32 + lq * 8];
      #pragma unroll
      for (int fn = 0; fn < 4; ++fn)
        vf[fn] = *(const short8*)&VT[(fn * 16 + l15) * 64 + kk * 32 + lq * 8];
      #pragma unroll
      for (int fm = 0; fm < 2; ++fm)
        #pragma unroll
        for (int fn = 0; fn < 4; ++fn)
          oacc[fm][fn] = __builtin_amdgcn_mfma_f32_16x16x32_bf16(pf[fm], vf[fn], oacc[fm][fn], 0, 0, 0);
    }
  }

  const int b = bh >> 4, h = bh & 15;
  #pragma unroll
  for (int fm = 0; fm < 2; ++fm)
    #pragma unroll
    for (int fn = 0; fn < 4; ++fn)
      #pragma unroll
      for (int r = 0; r < 4; ++r) {
        const int qpos = qblk * 128 + w * 32 + fm * 16 + lq * 4 + r;
        const int d = fn * 16 + l15;
        const float o = oacc[fm][fn][r] / lrun[fm][r];
        attn_out[(size_t)(b * 4096 + qpos) * 1024 + h * 64 + d] = f2bf(o);
      }
}

// ---------------- launch ----------------
extern "C" void kernel_launch(void* const* d_in, const int* in_sizes, int n_in,
                              void* d_out, int out_size, void* d_ws, size_t ws_size,
                              hipStream_t stream) {
  const float* x      = (const float*)d_in[0];
  const float* w_qkv  = (const float*)d_in[1];
  const float* w_proj = (const float*)d_in[2];
  const float* b_proj = (const float*)d_in[3];
  float* out = (float*)d_out;
  char* ws = (char*)d_ws;

  ushort_t* x16    = (ushort_t*)(ws);                 // 16,777,216  (also attn_out bf16)
  ushort_t* wqkvT  = (ushort_t*)(ws + 16777216);      //  6,291,456
  ushort_t* wprojT = (ushort_t*)(ws + 23068672);      //  2,097,152
  ushort_t* qbuf   = (ushort_t*)(ws + 25165824);      // 16,777,216
  ushort_t* kbuf   = (ushort_t*)(ws + 41943040);      // 16,777,216
  ushort_t* vbuf   = (ushort_t*)(ws + 58720256);      // 16,777,216 -> total 75,497,472
  ushort_t* attn16 = x16;

  conv_x<<<dim3(8192), dim3(256), 0, stream>>>(x, x16, 2097152);
  transpose_conv<<<dim3(96, 32), dim3(32, 8), 0, stream>>>(w_qkv, wqkvT, 1024, 3072);
  transpose_conv<<<dim3(32, 32), dim3(32, 8), 0, stream>>>(w_proj, wprojT, 1024, 1024);
  gemm256<0, 12><<<dim3(384), dim3(512), 0, stream>>>(x16, wqkvT, qbuf, kbuf, vbuf, nullptr, nullptr, 384);
  swin_attn<<<dim3(32, 32), dim3(256), 0, stream>>>(qbuf, kbuf, vbuf, attn16);
  gemm256<1, 4><<<dim3(128), dim3(512), 0, stream>>>(attn16, wprojT, nullptr, nullptr, nullptr, b_proj, out, 128);
}